// Round 4
// baseline (265.889 us; speedup 1.0000x reference)
//
#include <hip/hip_runtime.h>
#include <math.h>

typedef float f32x4 __attribute__((ext_vector_type(4)));

namespace {
constexpr int kDim = 2048;
constexpr int kH = 16;
constexpr int kD = 128;
constexpr int kS = 8192;
constexpr int kChunk = 128;            // keys per attn block
constexpr int kNChunk = kS / kChunk;   // 64
constexpr float kScale = 0.08838834764831843f; // 1/sqrt(128)
} // namespace

__device__ __forceinline__ f32x4 ntload4(const float* p) {
    return __builtin_nontemporal_load(reinterpret_cast<const f32x4*>(p));
}

// One wave per output row. Rows [0,2048)=w_q, [2048,4096)=w_k, [4096,6144)=w_v.
// Also zeroes the per-head combine counters (runs before attn_fused in stream order).
__global__ __launch_bounds__(256) void qkv_gemv(
    const float* __restrict__ x, const float* __restrict__ wq,
    const float* __restrict__ wk, const float* __restrict__ wv,
    float* __restrict__ qkv, int* __restrict__ cnt)
{
    if (blockIdx.x == 0 && threadIdx.x < kH) cnt[threadIdx.x] = 0;
    const int wid  = (blockIdx.x << 2) | ((int)threadIdx.x >> 6);
    const int lane = threadIdx.x & 63;
    const float* W;
    int r = wid;
    if (r < kDim)            { W = wq; }
    else if (r < 2 * kDim)   { W = wk; r -= kDim; }
    else                     { W = wv; r -= 2 * kDim; }
    const float* wrow = W + (size_t)r * kDim;
    const float4* x4  = reinterpret_cast<const float4*>(x);
    f32x4  wr[8];
    float4 xv[8];
#pragma unroll
    for (int k = 0; k < 8; ++k) wr[k] = ntload4(wrow + (((k << 6) + lane) << 2));
#pragma unroll
    for (int k = 0; k < 8; ++k) xv[k] = x4[(k << 6) + lane];
    float acc = 0.f;
#pragma unroll
    for (int k = 0; k < 8; ++k)
        acc += wr[k].x * xv[k].x + wr[k].y * xv[k].y
             + wr[k].z * xv[k].z + wr[k].w * xv[k].w;
#pragma unroll
    for (int off = 32; off; off >>= 1) acc += __shfl_xor(acc, off, 64);
    if (lane == 0) qkv[wid] = acc;
}

// Fused attention: one block per (head, 128-key chunk).
// Phase 1: scores -> LDS (kq/q lane map: 16 keys/wave/group, 4 lanes per key).
// Phase 2: chunk max + exp (identical math to split version).
// Phase 3: streaming PV (half-wave map: 2 keys/instr, 8 loads in flight).
// Phase 4: last block per head combines all 64 partials (threadfence+atomic).
__global__ __launch_bounds__(256) void attn_fused(
    const float* __restrict__ k_cache, const float* __restrict__ v_cache,
    const float* __restrict__ qkv, const int* __restrict__ pos_p,
    float* __restrict__ part, float* __restrict__ o_out, int* __restrict__ cnt)
{
    const int h     = blockIdx.x >> 6;
    const int chunk = blockIdx.x & (kNChunk - 1);
    const int wave  = threadIdx.x >> 6;
    const int lane  = threadIdx.x & 63;
    const int t     = threadIdx.x;
    const int pos   = pos_p[0];
    const int s0    = chunk * kChunk;

    __shared__ float  s_lds[kChunk];     // scores, then e = exp(s - M)
    __shared__ float  wred[4];
    __shared__ float4 sacc[4][32];
    __shared__ float  f_lds[kNChunk];    // combine factors (last block only)
    __shared__ float  Lg_s;
    __shared__ int    is_last;

    const float* knew = qkv + kDim + h * kD;
    const float* vnew = qkv + 2 * kDim + h * kD;

    // ---- Phase 1: scores ----
    {
        const int kq = lane >> 2;
        const int q  = lane & 3;
        const float4* q4p = reinterpret_cast<const float4*>(qkv + h * kD + q * 32);
        float4 qv[8];
#pragma unroll
        for (int i = 0; i < 8; ++i) qv[i] = q4p[i];
#pragma unroll
        for (int g = 0; g < 2; ++g) {
            const int key = s0 + wave * 32 + g * 16 + kq;
            const float* kp = ((key == pos) ? knew
                                            : (k_cache + (size_t)key * kDim + h * kD)) + q * 32;
            f32x4 kv[8];
#pragma unroll
            for (int i = 0; i < 8; ++i) kv[i] = ntload4(kp + (i << 2));
            float s = 0.f;
#pragma unroll
            for (int i = 0; i < 8; ++i)
                s += kv[i].x * qv[i].x + kv[i].y * qv[i].y
                   + kv[i].z * qv[i].z + kv[i].w * qv[i].w;
            s += __shfl_xor(s, 1, 64);
            s += __shfl_xor(s, 2, 64);
            if (q == 0)
                s_lds[wave * 32 + g * 16 + kq] = (key <= pos) ? s * kScale : -INFINITY;
        }
    }
    __syncthreads();

    // ---- Phase 2: chunk max + exp ----
    const float sc_t = (t < kChunk) ? s_lds[t] : -INFINITY;
    {
        float mx = sc_t;
#pragma unroll
        for (int m = 32; m; m >>= 1) mx = fmaxf(mx, __shfl_xor(mx, m, 64));
        if (lane == 0) wred[wave] = mx;
    }
    __syncthreads();
    const float M = fmaxf(fmaxf(wred[0], wred[1]), fmaxf(wred[2], wred[3]));
    if (t < kChunk) s_lds[t] = (M > -INFINITY) ? __expf(sc_t - M) : 0.f;
    __syncthreads();

    // ---- Phase 3: PV ----
    {
        const int half = lane >> 5;
        const int l32  = lane & 31;
        f32x4 v[8];
        float ev[8];
        float4 acc = make_float4(0.f, 0.f, 0.f, 0.f);
#pragma unroll
        for (int g = 0; g < 2; ++g) {
#pragma unroll
            for (int it = 0; it < 8; ++it) {
                const int key = s0 + wave * 32 + g * 16 + 2 * it + half;
                const float* vp = (key == pos) ? vnew
                                               : (v_cache + (size_t)key * kDim + h * kD);
                v[it] = ntload4(vp + (l32 << 2));
            }
#pragma unroll
            for (int it = 0; it < 8; ++it)
                ev[it] = s_lds[wave * 32 + g * 16 + 2 * it + half];
#pragma unroll
            for (int it = 0; it < 8; ++it) {
                acc.x += ev[it] * v[it].x;
                acc.y += ev[it] * v[it].y;
                acc.z += ev[it] * v[it].z;
                acc.w += ev[it] * v[it].w;
            }
        }
        acc.x += __shfl_xor(acc.x, 32, 64);
        acc.y += __shfl_xor(acc.y, 32, 64);
        acc.z += __shfl_xor(acc.z, 32, 64);
        acc.w += __shfl_xor(acc.w, 32, 64);
        if (half == 0) sacc[wave][l32] = acc;
    }
    __syncthreads();

    if (wave == 0 && lane < 32) {
        const int l32 = lane;
        float4 A = sacc[0][l32];
        const float4 B = sacc[1][l32], C = sacc[2][l32], D = sacc[3][l32];
        A.x += B.x + C.x + D.x;
        A.y += B.y + C.y + D.y;
        A.z += B.z + C.z + D.z;
        A.w += B.w + C.w + D.w;
        float le = s_lds[l32] + s_lds[l32 + 32] + s_lds[l32 + 64] + s_lds[l32 + 96];
#pragma unroll
        for (int m = 16; m; m >>= 1) le += __shfl_xor(le, m, 64);
        float* pp = part + (size_t)(h * kNChunk + chunk) * (kD + 2);
        reinterpret_cast<float4*>(pp)[l32] = A;
        if (l32 == 0) { pp[kD] = M; pp[kD + 1] = le; }
    }

    // ---- Phase 4: last block per head combines ----
    __threadfence();
    __syncthreads();
    if (t == 0) {
        const int prev = atomicAdd(&cnt[h], 1);
        is_last = (prev == kNChunk - 1) ? 1 : 0;
    }
    __syncthreads();
    if (!is_last) return;
    __threadfence();  // acquire: see other blocks' partials

    const float* pbase = part + (size_t)h * kNChunk * (kD + 2);
    float mc = -INFINITY, lc = 0.f;
    if (t < kNChunk) {
        mc = pbase[(size_t)t * (kD + 2) + kD];
        lc = pbase[(size_t)t * (kD + 2) + kD + 1];
    }
    if (t < 64) {
        float Mg = mc;
#pragma unroll
        for (int m = 32; m; m >>= 1) Mg = fmaxf(Mg, __shfl_xor(Mg, m, 64));
        const float f = (lc > 0.f) ? __expf(mc - Mg) : 0.f;
        f_lds[t] = f;
        float lf = lc * f;
#pragma unroll
        for (int m = 32; m; m >>= 1) lf += __shfl_xor(lf, m, 64);
        if (t == 0) Lg_s = lf;
    }
    __syncthreads();
    if (t < kD) {
        float O = 0.f;
#pragma unroll 8
        for (int c = 0; c < kNChunk; ++c)
            O += pbase[(size_t)c * (kD + 2) + t] * f_lds[c];
        o_out[h * kD + t] = O / Lg_s;
    }
}

// Output projection GEMV: one wave per output row.
__global__ __launch_bounds__(256) void out_gemv(
    const float* __restrict__ o, const float* __restrict__ wo,
    float* __restrict__ out)
{
    const int wid  = (blockIdx.x << 2) | ((int)threadIdx.x >> 6);
    const int lane = threadIdx.x & 63;
    const float* wrow = wo + (size_t)wid * kDim;
    const float4* x4  = reinterpret_cast<const float4*>(o);
    f32x4  wr[8];
    float4 xv[8];
#pragma unroll
    for (int k = 0; k < 8; ++k) wr[k] = ntload4(wrow + (((k << 6) + lane) << 2));
#pragma unroll
    for (int k = 0; k < 8; ++k) xv[k] = x4[(k << 6) + lane];
    float acc = 0.f;
#pragma unroll
    for (int k = 0; k < 8; ++k)
        acc += wr[k].x * xv[k].x + wr[k].y * xv[k].y
             + wr[k].z * xv[k].z + wr[k].w * xv[k].w;
#pragma unroll
    for (int off = 32; off; off >>= 1) acc += __shfl_xor(acc, off, 64);
    if (lane == 0) out[wid] = acc;
}

extern "C" void kernel_launch(void* const* d_in, const int* in_sizes, int n_in,
                              void* d_out, int out_size, void* d_ws, size_t ws_size,
                              hipStream_t stream)
{
    const float* x       = (const float*)d_in[0];
    const float* k_cache = (const float*)d_in[1];
    const float* v_cache = (const float*)d_in[2];
    const float* wq      = (const float*)d_in[3];
    const float* wk      = (const float*)d_in[4];
    const float* wv      = (const float*)d_in[5];
    const float* wo      = (const float*)d_in[6];
    const int*   pos     = (const int*)d_in[7];
    float* out = (float*)d_out;

    float* ws    = (float*)d_ws;
    float* qkv   = ws;                                   // 3*2048
    float* part  = qkv + 3 * kDim;                       // 16*64*130
    float* o_out = part + kH * kNChunk * (kD + 2);       // 2048
    int*   cnt   = (int*)(o_out + kDim);                 // 16 ints

    qkv_gemv<<<3 * kDim / 4, 256, 0, stream>>>(x, wq, wk, wv, qkv, cnt);
    attn_fused<<<kH * kNChunk, 256, 0, stream>>>(k_cache, v_cache, qkv, pos, part, o_out, cnt);
    out_gemv<<<kDim / 4, 256, 0, stream>>>(o_out, wo, out);
}

// Round 5
// 44.739 us; speedup vs baseline: 5.9431x; 5.9431x over previous
//
#include <hip/hip_runtime.h>
#include <math.h>

namespace {
constexpr int kDim = 2048;
constexpr int kH = 16;
constexpr int kD = 128;
constexpr int kS = 8192;
constexpr int kChunk = 128;            // keys per attn block
constexpr int kNChunk = kS / kChunk;   // 64
constexpr float kScale = 0.08838834764831843f; // 1/sqrt(128)
} // namespace

// One wave per output row. Rows [0,2048)=w_q, [2048,4096)=w_k, [4096,6144)=w_v.
__global__ __launch_bounds__(256) void qkv_gemv(
    const float* __restrict__ x, const float* __restrict__ wq,
    const float* __restrict__ wk, const float* __restrict__ wv,
    float* __restrict__ qkv)
{
    const int wid  = (blockIdx.x << 2) | ((int)threadIdx.x >> 6);
    const int lane = threadIdx.x & 63;
    const float* W;
    int r = wid;
    if (r < kDim)            { W = wq; }
    else if (r < 2 * kDim)   { W = wk; r -= kDim; }
    else                     { W = wv; r -= 2 * kDim; }
    const float4* wrow = reinterpret_cast<const float4*>(W + (size_t)r * kDim);
    const float4* x4   = reinterpret_cast<const float4*>(x);
    float4 wr[8], xv[8];
#pragma unroll
    for (int k = 0; k < 8; ++k) wr[k] = wrow[(k << 6) + lane];
#pragma unroll
    for (int k = 0; k < 8; ++k) xv[k] = x4[(k << 6) + lane];
    float acc = 0.f;
#pragma unroll
    for (int k = 0; k < 8; ++k)
        acc += wr[k].x * xv[k].x + wr[k].y * xv[k].y
             + wr[k].z * xv[k].z + wr[k].w * xv[k].w;
#pragma unroll
    for (int off = 32; off; off >>= 1) acc += __shfl_xor(acc, off, 64);
    if (lane == 0) qkv[wid] = acc;
}

// Fused attention: one block per (head, 128-key chunk).
// Phase 1: scores -> LDS. Phase 2: chunk max + exp. Phase 3: streaming PV.
// Partials {o[128], M, l} go to ws; combine happens in a separate tiny kernel.
__global__ __launch_bounds__(256) void attn_fused(
    const float* __restrict__ k_cache, const float* __restrict__ v_cache,
    const float* __restrict__ qkv, const int* __restrict__ pos_p,
    float* __restrict__ part)
{
    const int h     = blockIdx.x >> 6;
    const int chunk = blockIdx.x & (kNChunk - 1);
    const int wave  = threadIdx.x >> 6;
    const int lane  = threadIdx.x & 63;
    const int t     = threadIdx.x;
    const int pos   = pos_p[0];
    const int s0    = chunk * kChunk;

    __shared__ float  s_lds[kChunk];     // scores, then e = exp(s - M)
    __shared__ float  wred[4];
    __shared__ float4 sacc[4][32];

    const float* knew = qkv + kDim + h * kD;
    const float* vnew = qkv + 2 * kDim + h * kD;

    // ---- Phase 1: scores (16 keys per wave per g; 4 lanes x 32 dims per key) ----
    {
        const int kq = lane >> 2;
        const int q  = lane & 3;
        const float4* q4p = reinterpret_cast<const float4*>(qkv + h * kD + q * 32);
        float4 qv[8];
#pragma unroll
        for (int i = 0; i < 8; ++i) qv[i] = q4p[i];
#pragma unroll
        for (int g = 0; g < 2; ++g) {
            const int key = s0 + wave * 32 + g * 16 + kq;
            const float4* kp = reinterpret_cast<const float4*>(
                ((key == pos) ? knew : (k_cache + (size_t)key * kDim + h * kD)) + q * 32);
            float4 kv[8];
#pragma unroll
            for (int i = 0; i < 8; ++i) kv[i] = kp[i];
            float s = 0.f;
#pragma unroll
            for (int i = 0; i < 8; ++i)
                s += kv[i].x * qv[i].x + kv[i].y * qv[i].y
                   + kv[i].z * qv[i].z + kv[i].w * qv[i].w;
            s += __shfl_xor(s, 1, 64);
            s += __shfl_xor(s, 2, 64);
            if (q == 0)
                s_lds[wave * 32 + g * 16 + kq] = (key <= pos) ? s * kScale : -INFINITY;
        }
    }
    __syncthreads();

    // ---- Phase 2: chunk max + exp ----
    const float sc_t = (t < kChunk) ? s_lds[t] : -INFINITY;
    {
        float mx = sc_t;
#pragma unroll
        for (int m = 32; m; m >>= 1) mx = fmaxf(mx, __shfl_xor(mx, m, 64));
        if (lane == 0) wred[wave] = mx;
    }
    __syncthreads();
    const float M = fmaxf(fmaxf(wred[0], wred[1]), fmaxf(wred[2], wred[3]));
    if (t < kChunk) s_lds[t] = (M > -INFINITY) ? __expf(sc_t - M) : 0.f;
    __syncthreads();

    // ---- Phase 3: PV (2 keys per instr via wave halves; 8 loads in flight) ----
    {
        const int half = lane >> 5;
        const int l32  = lane & 31;
        float4 v[8];
        float  ev[8];
        float4 acc = make_float4(0.f, 0.f, 0.f, 0.f);
#pragma unroll
        for (int g = 0; g < 2; ++g) {
#pragma unroll
            for (int it = 0; it < 8; ++it) {
                const int key = s0 + wave * 32 + g * 16 + 2 * it + half;
                const float* vp = (key == pos) ? vnew
                                               : (v_cache + (size_t)key * kDim + h * kD);
                v[it] = reinterpret_cast<const float4*>(vp)[l32];
            }
#pragma unroll
            for (int it = 0; it < 8; ++it)
                ev[it] = s_lds[wave * 32 + g * 16 + 2 * it + half];
#pragma unroll
            for (int it = 0; it < 8; ++it) {
                acc.x += ev[it] * v[it].x;
                acc.y += ev[it] * v[it].y;
                acc.z += ev[it] * v[it].z;
                acc.w += ev[it] * v[it].w;
            }
        }
        acc.x += __shfl_xor(acc.x, 32, 64);
        acc.y += __shfl_xor(acc.y, 32, 64);
        acc.z += __shfl_xor(acc.z, 32, 64);
        acc.w += __shfl_xor(acc.w, 32, 64);
        if (half == 0) sacc[wave][l32] = acc;
    }
    __syncthreads();

    if (wave == 0 && lane < 32) {
        const int l32 = lane;
        float4 A = sacc[0][l32];
        const float4 B = sacc[1][l32], C = sacc[2][l32], D = sacc[3][l32];
        A.x += B.x + C.x + D.x;
        A.y += B.y + C.y + D.y;
        A.z += B.z + C.z + D.z;
        A.w += B.w + C.w + D.w;
        float le = s_lds[l32] + s_lds[l32 + 32] + s_lds[l32 + 64] + s_lds[l32 + 96];
#pragma unroll
        for (int m = 16; m; m >>= 1) le += __shfl_xor(le, m, 64);
        float* pp = part + (size_t)(h * kNChunk + chunk) * (kD + 2);
        reinterpret_cast<float4*>(pp)[l32] = A;
        if (l32 == 0) { pp[kD] = M; pp[kD + 1] = le; }
    }
}

// Combine: one block per head. Per-chunk factors staged in LDS, then 64
// independent partial loads per thread.
__global__ __launch_bounds__(128) void combine_partials(
    const float* __restrict__ part, float* __restrict__ o_out)
{
    const int h = blockIdx.x;
    const int t = threadIdx.x;
    __shared__ float f_lds[kNChunk];
    __shared__ float Lg;

    float mc = -INFINITY, lc = 0.f;
    if (t < kNChunk) {
        const float* pp = part + (size_t)(h * kNChunk + t) * (kD + 2);
        mc = pp[kD];
        lc = pp[kD + 1];
    }
    if (t < 64) {
        float Mg = mc;
#pragma unroll
        for (int m = 32; m; m >>= 1) Mg = fmaxf(Mg, __shfl_xor(Mg, m, 64));
        const float f = (lc > 0.f) ? __expf(mc - Mg) : 0.f;
        f_lds[t] = f;
        float lf = lc * f;
#pragma unroll
        for (int m = 32; m; m >>= 1) lf += __shfl_xor(lf, m, 64);
        if (t == 0) Lg = lf;
    }
    __syncthreads();

    float O = 0.f;
    const float* base = part + (size_t)h * kNChunk * (kD + 2) + t;
#pragma unroll 8
    for (int c = 0; c < kNChunk; ++c)
        O += base[(size_t)c * (kD + 2)] * f_lds[c];
    o_out[h * kD + t] = O / Lg;
}

// Output projection GEMV: one wave per output row.
__global__ __launch_bounds__(256) void out_gemv(
    const float* __restrict__ o, const float* __restrict__ wo,
    float* __restrict__ out)
{
    const int wid  = (blockIdx.x << 2) | ((int)threadIdx.x >> 6);
    const int lane = threadIdx.x & 63;
    const float4* wrow = reinterpret_cast<const float4*>(wo + (size_t)wid * kDim);
    const float4* x4   = reinterpret_cast<const float4*>(o);
    float4 wr[8], xv[8];
#pragma unroll
    for (int k = 0; k < 8; ++k) wr[k] = wrow[(k << 6) + lane];
#pragma unroll
    for (int k = 0; k < 8; ++k) xv[k] = x4[(k << 6) + lane];
    float acc = 0.f;
#pragma unroll
    for (int k = 0; k < 8; ++k)
        acc += wr[k].x * xv[k].x + wr[k].y * xv[k].y
             + wr[k].z * xv[k].z + wr[k].w * xv[k].w;
#pragma unroll
    for (int off = 32; off; off >>= 1) acc += __shfl_xor(acc, off, 64);
    if (lane == 0) out[wid] = acc;
}

extern "C" void kernel_launch(void* const* d_in, const int* in_sizes, int n_in,
                              void* d_out, int out_size, void* d_ws, size_t ws_size,
                              hipStream_t stream)
{
    const float* x       = (const float*)d_in[0];
    const float* k_cache = (const float*)d_in[1];
    const float* v_cache = (const float*)d_in[2];
    const float* wq      = (const float*)d_in[3];
    const float* wk      = (const float*)d_in[4];
    const float* wv      = (const float*)d_in[5];
    const float* wo      = (const float*)d_in[6];
    const int*   pos     = (const int*)d_in[7];
    float* out = (float*)d_out;

    float* ws    = (float*)d_ws;
    float* qkv   = ws;                                   // 3*2048
    float* part  = qkv + 3 * kDim;                       // 16*64*130
    float* o_out = part + kH * kNChunk * (kD + 2);       // 2048

    qkv_gemv<<<3 * kDim / 4, 256, 0, stream>>>(x, wq, wk, wv, qkv);
    attn_fused<<<kH * kNChunk, 256, 0, stream>>>(k_cache, v_cache, qkv, pos, part);
    combine_partials<<<kH, 128, 0, stream>>>(part, o_out);
    out_gemv<<<kDim / 4, 256, 0, stream>>>(o_out, wo, out);
}